// Round 8
// baseline (105.548 us; speedup 1.0000x reference)
//
#include <hip/hip_runtime.h>
#include <hip/hip_bf16.h>
#include <math.h>

// VectorQuantizer: z [65536 x 64] fp32, codebook [1024 x 64] fp32.
// dist = (||z||^2 - 2 z.e) + ||e||^2, argmin_k, first-occurrence ties.
// Numerics identical to R4-R14 (absmax 0): exact np pairwise sumsq for S/cn;
// d via f16 split-2 3-pass MFMA; dist = (S - 2d) + cn explicit __f*_rn;
// (val, lowest-k) reduce. MFMA accumulation order preserved bit-exactly.
//
// R15 -> R16: compile fix only. __builtin_nontemporal_store requires a
// Clang vector type; HIP's uint4 is a struct. Use ext_vector_type(4) uint.
// Theory under test (H5, unchanged): ef/cn are written by vq_pre on ~16
// CUs and sit DIRTY in those XCDs' L2s; 7/8 of vq_main's reads are
// cross-XCD and must resolve a remote-dirty line (probe+writeback,
// ~1000cy, serialized at the owning L2) -- identical for DMA and register
// loads, invisible in FETCH_SIZE, re-created every iteration by vq_pre.
// Fix: nt stores (don't retain dirty in L2) + __threadfence_system()
// (L2 writeback) so vq_main reads CLEAN L3 lines. Main loop = R13.

#define D      64
#define K      1024
#define BLOCK  256

typedef _Float16 half8_t __attribute__((ext_vector_type(8)));
typedef float    floatx4 __attribute__((ext_vector_type(4)));
typedef unsigned int uint4v __attribute__((ext_vector_type(4)));

// ws layout
#define WS_CN_OFF    0            // float[1024]         (4 KB)
#define WS_EF_OFF    4096         // _Float16[131072]    (256 KB)
// group-contiguous layout: group g = t*4+ct (16 codes) occupies bytes
// [g*4096, (g+1)*4096): slot s=(spl*2+ch) at g*4096 + s*1024 + 16*lane,
// lane = quad*16 + l16 (MFMA B lane order).

// numpy pairwise sumsq (n=64): 8 stride-8 accs of fl(x^2), tree combine.
__device__ __forceinline__ float np_sumsq64_p(const float* __restrict__ x) {
    float r[8];
    {
        float4 v0 = *(const float4*)(x);
        float4 v1 = *(const float4*)(x + 4);
        r[0] = __fmul_rn(v0.x, v0.x); r[1] = __fmul_rn(v0.y, v0.y);
        r[2] = __fmul_rn(v0.z, v0.z); r[3] = __fmul_rn(v0.w, v0.w);
        r[4] = __fmul_rn(v1.x, v1.x); r[5] = __fmul_rn(v1.y, v1.y);
        r[6] = __fmul_rn(v1.z, v1.z); r[7] = __fmul_rn(v1.w, v1.w);
    }
#pragma unroll
    for (int i = 8; i < 64; i += 8) {
        float4 v0 = *(const float4*)(x + i);
        float4 v1 = *(const float4*)(x + i + 4);
        r[0] = __fadd_rn(r[0], __fmul_rn(v0.x, v0.x));
        r[1] = __fadd_rn(r[1], __fmul_rn(v0.y, v0.y));
        r[2] = __fadd_rn(r[2], __fmul_rn(v0.z, v0.z));
        r[3] = __fadd_rn(r[3], __fmul_rn(v0.w, v0.w));
        r[4] = __fadd_rn(r[4], __fmul_rn(v1.x, v1.x));
        r[5] = __fadd_rn(r[5], __fmul_rn(v1.y, v1.y));
        r[6] = __fadd_rn(r[6], __fmul_rn(v1.z, v1.z));
        r[7] = __fadd_rn(r[7], __fmul_rn(v1.w, v1.w));
    }
    return __fadd_rn(__fadd_rn(__fadd_rn(r[0], r[1]), __fadd_rn(r[2], r[3])),
                     __fadd_rn(__fadd_rn(r[4], r[5]), __fadd_rn(r[6], r[7])));
}

__device__ __forceinline__ void nt_store16(_Float16* p, half8_t v) {
    uint4v u;
    __builtin_memcpy(&u, &v, 16);
    __builtin_nontemporal_store(u, (uint4v*)p);
}

// ---- precompute: code norms + f16 split-2 B-frags, group-contiguous ----
// nt stores + system fence: leave ef/cn CLEAN in L3, not dirty in L2.
__global__ void vq_pre(const float* __restrict__ cb, float* __restrict__ cn,
                       _Float16* __restrict__ ef) {
    const int k = blockIdx.x * 64 + threadIdx.x;
    if (k < K) {
        __builtin_nontemporal_store(np_sumsq64_p(cb + (long)k * D), &cn[k]);
        const int t = k >> 6, ct = (k >> 4) & 3, l16 = k & 15;
#pragma unroll
        for (int ch = 0; ch < 2; ++ch)
#pragma unroll
            for (int quad = 0; quad < 4; ++quad) {
                const float* p = cb + (long)k * D + ch * 32 + quad * 8;
                half8_t h1, h2;
#pragma unroll
                for (int j = 0; j < 8; ++j) {
                    float x10 = __fmul_rn(p[j], 1024.0f);    // exact pow2 scale
                    _Float16 g1 = (_Float16)x10;
                    h1[j] = g1;
                    h2[j] = (_Float16)(__fmul_rn(__fsub_rn(x10, (float)g1), 2048.0f));
                }
                // half-offset within group: slot*512 + 128*quad + 8*l16
                const int base = t * 8192 + ct * 2048 + 128 * quad + 8 * l16;
                nt_store16(ef + base + 512 * (ch), h1);       // spl0: slots 0,1
                nt_store16(ef + base + 512 * (2 + ch), h2);   // spl1: slots 2,3
            }
    }
    // force dirty lines out of this XCD's L2 to L3 before vq_main reads
    __threadfence_system();
}

// ---- main: 128 rows x ALL 1024 codes per 4-wave block; barrier-free loop ----
__global__ __launch_bounds__(BLOCK, 2) void vq_main(
    const float* __restrict__ z, const float* __restrict__ cb,
    const _Float16* __restrict__ ef, const float* __restrict__ cn,
    float* __restrict__ zq, float* __restrict__ idx_out) {
    __shared__ __align__(16) float zf[128 * 68];   // 34816 B, +68 stride
    __shared__ float sS[128];
    __shared__ float sCn[K];
    __shared__ int   sBi[128];

    const int tid  = threadIdx.x;
    const int lane = tid & 63;
    const int wv   = tid >> 6;
    const int quad = lane >> 4;
    const int l16  = lane & 15;
    const long rowbase = (long)blockIdx.x * 128;

    // ---- stage z (coalesced) + all code norms ----
    const float4* gz = (const float4*)(z + rowbase * D);
#pragma unroll
    for (int i = 0; i < 8; ++i) {
        int idx4 = i * BLOCK + tid;
        int r = idx4 >> 4, j = idx4 & 15;
        *(float4*)(zf + r * 68 + j * 4) = gz[idx4];
    }
#pragma unroll
    for (int i = 0; i < 4; ++i) sCn[i * 256 + tid] = cn[i * 256 + tid];
    __syncthreads();

    // row norms (exact np chain)
    if (tid < 128) sS[tid] = np_sumsq64_p(zf + tid * 68);

    // A-frags: register-resident f16 splits; wave wv -> rows wv*32 .. +31
    half8_t a1[2][2], a2[2][2];
#pragma unroll
    for (int rt = 0; rt < 2; ++rt) {
        const int row = wv * 32 + rt * 16 + l16;
#pragma unroll
        for (int ch = 0; ch < 2; ++ch) {
            const float* p = zf + row * 68 + ch * 32 + quad * 8;
            float4 f0 = *(const float4*)(p);
            float4 f1 = *(const float4*)(p + 4);
            float xs[8] = {f0.x, f0.y, f0.z, f0.w, f1.x, f1.y, f1.z, f1.w};
#pragma unroll
            for (int j = 0; j < 8; ++j) {
                _Float16 h1 = (_Float16)xs[j];
                a1[rt][ch][j] = h1;
                a2[rt][ch][j] =
                    (_Float16)(__fmul_rn(__fsub_rn(xs[j], (float)h1), 2048.0f));
            }
        }
    }
    __syncthreads();   // sS visible to all waves

    float myS[2][4];
#pragma unroll
    for (int rt = 0; rt < 2; ++rt)
#pragma unroll
        for (int r = 0; r < 4; ++r)
            myS[rt][r] = sS[wv * 32 + rt * 16 + quad * 4 + r];

    float bv[2][4];
    int   bi[2][4];
#pragma unroll
    for (int rt = 0; rt < 2; ++rt)
#pragma unroll
        for (int r = 0; r < 4; ++r) { bv[rt][r] = INFINITY; bi[rt][r] = 0; }

    const char* eb = (const char*)ef + 16 * lane;
    const floatx4 Z4g = {0.f, 0.f, 0.f, 0.f};      // single zero acc quad

// 4 streaming 1KB global loads (L3-clean, locally cacheable) + cnv prefetch
#define LOADG(b1_, b2_, cnv_, g_) do {                                        \
        const char* p_ = eb + (size_t)(g_) * 4096;                            \
        b1_[0] = *(const half8_t*)(p_);                                       \
        b1_[1] = *(const half8_t*)(p_ + 1024);                                \
        b2_[0] = *(const half8_t*)(p_ + 2048);                                \
        b2_[1] = *(const half8_t*)(p_ + 3072);                                \
        cnv_   = sCn[(g_) * 16 + l16];                                        \
    } while (0)

// 12 MFMAs (rt0/rt1 interleaved; per-element accumulation order = R8)
// + exact EPI: ds=fma(aC,2^-11,aM); t2=ds*2^-9; dist=(S-t2)+cn; strict <.
#define COMPUTE(b1_, b2_, cnv_, g_) do {                                      \
        const int kg_ = (g_) * 16 + l16;                                      \
        floatx4 aM0, aM1, aC0, aC1;                                           \
        aM0 = __builtin_amdgcn_mfma_f32_16x16x32_f16(a1[0][0], b1_[0], Z4g, 0, 0, 0); \
        aM1 = __builtin_amdgcn_mfma_f32_16x16x32_f16(a1[1][0], b1_[0], Z4g, 0, 0, 0); \
        aM0 = __builtin_amdgcn_mfma_f32_16x16x32_f16(a1[0][1], b1_[1], aM0, 0, 0, 0); \
        aM1 = __builtin_amdgcn_mfma_f32_16x16x32_f16(a1[1][1], b1_[1], aM1, 0, 0, 0); \
        aC0 = __builtin_amdgcn_mfma_f32_16x16x32_f16(a1[0][0], b2_[0], Z4g, 0, 0, 0); \
        aC1 = __builtin_amdgcn_mfma_f32_16x16x32_f16(a1[1][0], b2_[0], Z4g, 0, 0, 0); \
        aC0 = __builtin_amdgcn_mfma_f32_16x16x32_f16(a1[0][1], b2_[1], aC0, 0, 0, 0); \
        aC1 = __builtin_amdgcn_mfma_f32_16x16x32_f16(a1[1][1], b2_[1], aC1, 0, 0, 0); \
        aC0 = __builtin_amdgcn_mfma_f32_16x16x32_f16(a2[0][0], b1_[0], aC0, 0, 0, 0); \
        aC1 = __builtin_amdgcn_mfma_f32_16x16x32_f16(a2[1][0], b1_[0], aC1, 0, 0, 0); \
        aC0 = __builtin_amdgcn_mfma_f32_16x16x32_f16(a2[0][1], b1_[1], aC0, 0, 0, 0); \
        aC1 = __builtin_amdgcn_mfma_f32_16x16x32_f16(a2[1][1], b1_[1], aC1, 0, 0, 0); \
        _Pragma("unroll")                                                     \
        for (int r = 0; r < 4; ++r) {                                         \
            float ds0 = fmaf(aC0[r], 0x1p-11f, aM0[r]);                       \
            float d0  = __fadd_rn(__fsub_rn(myS[0][r],                        \
                            __fmul_rn(ds0, 0x1p-9f)), cnv_);                  \
            if (d0 < bv[0][r]) { bv[0][r] = d0; bi[0][r] = kg_; }             \
            float ds1 = fmaf(aC1[r], 0x1p-11f, aM1[r]);                       \
            float d1  = __fadd_rn(__fsub_rn(myS[1][r],                        \
                            __fmul_rn(ds1, 0x1p-9f)), cnv_);                  \
            if (d1 < bv[1][r]) { bv[1][r] = d1; bi[1][r] = kg_; }             \
        }                                                                     \
    } while (0)

    // depth-3 register pipeline over 64 groups; no barriers, waves free-run.
    half8_t b1A[2], b2A[2], b1B[2], b2B[2], b1C[2], b2C[2];
    float cnvA, cnvB, cnvC;
    LOADG(b1A, b2A, cnvA, 0);
    LOADG(b1B, b2B, cnvB, 1);
    for (int g = 0; g < 63; g += 3) {
        LOADG(b1C, b2C, cnvC, g + 2);
        COMPUTE(b1A, b2A, cnvA, g);
        if (g + 3 < 64) LOADG(b1A, b2A, cnvA, g + 3);
        COMPUTE(b1B, b2B, cnvB, g + 1);
        if (g + 4 < 64) LOADG(b1B, b2B, cnvB, g + 4);
        COMPUTE(b1C, b2C, cnvC, g + 2);
    }
    COMPUTE(b1A, b2A, cnvA, 63);   // loaded in the g=60 iteration

#undef LOADG
#undef COMPUTE

    // reduce over the 16 code-columns; (val, lowest index) = first occurrence
#pragma unroll
    for (int rt = 0; rt < 2; ++rt)
#pragma unroll
        for (int r = 0; r < 4; ++r) {
            float v = bv[rt][r];
            int   x = bi[rt][r];
#pragma unroll
            for (int off = 1; off <= 8; off <<= 1) {
                float ov = __shfl_xor(v, off);
                int   ox = __shfl_xor(x, off);
                if (ov < v || (ov == v && ox < x)) { v = ov; x = ox; }
            }
            if (l16 == 0) {
                const int rl = wv * 32 + rt * 16 + quad * 4 + r;
                sBi[rl] = x;
                idx_out[rowbase + rl] = (float)x;
            }
        }
    __syncthreads();

    // ---- zq gather: zq[row] = cb[bi[row]] (cb L2-hot, coalesced writes) ----
    const float4* cb4 = (const float4*)cb;
    float4* zq4 = (float4*)(zq + rowbase * D);
#pragma unroll
    for (int i = 0; i < 8; ++i) {
        int idx4 = i * BLOCK + tid;
        int r = idx4 >> 4, j = idx4 & 15;
        zq4[idx4] = cb4[(long)sBi[r] * 16 + j];
    }
}

extern "C" void kernel_launch(void* const* d_in, const int* in_sizes, int n_in,
                              void* d_out, int out_size, void* d_ws, size_t ws_size,
                              hipStream_t stream) {
    const float* z  = (const float*)d_in[0];
    const float* cb = (const float*)d_in[1];

    const int n_rows = in_sizes[0] / D;                 // 65536
    float* zq      = (float*)d_out;
    float* idx_out = zq + (long)n_rows * D;

    float*    ws_cn = (float*)((char*)d_ws + WS_CN_OFF);
    _Float16* ws_ef = (_Float16*)((char*)d_ws + WS_EF_OFF);

    vq_pre<<<K / 64, 64, 0, stream>>>(cb, ws_cn, ws_ef);
    vq_main<<<n_rows / 128, BLOCK, 0, stream>>>(z, cb, ws_ef, ws_cn, zq, idx_out);
}

// Round 9
// 101.595 us; speedup vs baseline: 1.0389x; 1.0389x over previous
//
#include <hip/hip_runtime.h>
#include <hip/hip_bf16.h>
#include <math.h>

// VectorQuantizer: z [65536 x 64] fp32, codebook [1024 x 64] fp32.
// dist = (||z||^2 - 2 z.e) + ||e||^2, argmin_k, first-occurrence ties.
// Numerics identical to R4-R16 (absmax 0): exact np pairwise sumsq for S/cn;
// d via f16 split-2 3-pass MFMA; dist = (S - 2d) + cn explicit __f*_rn;
// (val, lowest-k) reduce. MFMA accumulation order preserved bit-exactly.
//
// R16 post-mortem: H5 (dirty-L2) null. The real invariant: VGPR=68 in
// EVERY variant -> regalloc fully serialized the loads (load -> vmcnt(0)
// -> use -> reuse quad), effective pipeline depth ~0.25. 256 serial
// L2-hit loads x (~225cy + ~90cy compute) = ~35-40us == the 44us wall.
// C++ rotations collapse at IR level (R13), sched_barrier only pins the
// machine scheduler (R14), LDS variant trades this for barrier drain (R8).
// R17: loads in VOLATILE INLINE ASM (cannot collapse) + hand-counted
// s_waitcnt vmcnt(N) + sched_barrier(0) after each wait (rule #18).
// Depth-4 rotation, 16 loads in flight, each slot waited ~3 compute
// groups (~900cy) after issue; vmcnt drains 12/8/4/0 only in the tail.
// Readouts: VGPR must jump >=130; dur_us.

#define D      64
#define K      1024
#define BLOCK  256

typedef _Float16 half8_t __attribute__((ext_vector_type(8)));
typedef float    floatx4 __attribute__((ext_vector_type(4)));
typedef unsigned int uint4v __attribute__((ext_vector_type(4)));

// ws layout
#define WS_CN_OFF    0            // float[1024]         (4 KB)
#define WS_EF_OFF    4096         // _Float16[131072]    (256 KB)
// group-contiguous layout: group g = t*4+ct (16 codes) occupies bytes
// [g*4096, (g+1)*4096): slot s=(spl*2+ch) at g*4096 + s*1024 + 16*lane,
// lane = quad*16 + l16 (MFMA B lane order).

// numpy pairwise sumsq (n=64): 8 stride-8 accs of fl(x^2), tree combine.
__device__ __forceinline__ float np_sumsq64_p(const float* __restrict__ x) {
    float r[8];
    {
        float4 v0 = *(const float4*)(x);
        float4 v1 = *(const float4*)(x + 4);
        r[0] = __fmul_rn(v0.x, v0.x); r[1] = __fmul_rn(v0.y, v0.y);
        r[2] = __fmul_rn(v0.z, v0.z); r[3] = __fmul_rn(v0.w, v0.w);
        r[4] = __fmul_rn(v1.x, v1.x); r[5] = __fmul_rn(v1.y, v1.y);
        r[6] = __fmul_rn(v1.z, v1.z); r[7] = __fmul_rn(v1.w, v1.w);
    }
#pragma unroll
    for (int i = 8; i < 64; i += 8) {
        float4 v0 = *(const float4*)(x + i);
        float4 v1 = *(const float4*)(x + i + 4);
        r[0] = __fadd_rn(r[0], __fmul_rn(v0.x, v0.x));
        r[1] = __fadd_rn(r[1], __fmul_rn(v0.y, v0.y));
        r[2] = __fadd_rn(r[2], __fmul_rn(v0.z, v0.z));
        r[3] = __fadd_rn(r[3], __fmul_rn(v0.w, v0.w));
        r[4] = __fadd_rn(r[4], __fmul_rn(v1.x, v1.x));
        r[5] = __fadd_rn(r[5], __fmul_rn(v1.y, v1.y));
        r[6] = __fadd_rn(r[6], __fmul_rn(v1.z, v1.z));
        r[7] = __fadd_rn(r[7], __fmul_rn(v1.w, v1.w));
    }
    return __fadd_rn(__fadd_rn(__fadd_rn(r[0], r[1]), __fadd_rn(r[2], r[3])),
                     __fadd_rn(__fadd_rn(r[4], r[5]), __fadd_rn(r[6], r[7])));
}

__device__ __forceinline__ void nt_store16(_Float16* p, half8_t v) {
    uint4v u;
    __builtin_memcpy(&u, &v, 16);
    __builtin_nontemporal_store(u, (uint4v*)p);
}

// ---- precompute: code norms + f16 split-2 B-frags, group-contiguous ----
__global__ void vq_pre(const float* __restrict__ cb, float* __restrict__ cn,
                       _Float16* __restrict__ ef) {
    const int k = blockIdx.x * 64 + threadIdx.x;
    if (k < K) {
        __builtin_nontemporal_store(np_sumsq64_p(cb + (long)k * D), &cn[k]);
        const int t = k >> 6, ct = (k >> 4) & 3, l16 = k & 15;
#pragma unroll
        for (int ch = 0; ch < 2; ++ch)
#pragma unroll
            for (int quad = 0; quad < 4; ++quad) {
                const float* p = cb + (long)k * D + ch * 32 + quad * 8;
                half8_t h1, h2;
#pragma unroll
                for (int j = 0; j < 8; ++j) {
                    float x10 = __fmul_rn(p[j], 1024.0f);    // exact pow2 scale
                    _Float16 g1 = (_Float16)x10;
                    h1[j] = g1;
                    h2[j] = (_Float16)(__fmul_rn(__fsub_rn(x10, (float)g1), 2048.0f));
                }
                // half-offset within group: slot*512 + 128*quad + 8*l16
                const int base = t * 8192 + ct * 2048 + 128 * quad + 8 * l16;
                nt_store16(ef + base + 512 * (ch), h1);       // spl0: slots 0,1
                nt_store16(ef + base + 512 * (2 + ch), h2);   // spl1: slots 2,3
            }
    }
    __threadfence_system();   // ef/cn clean in L3 before vq_main reads
}

// ---- main: 128 rows x ALL 1024 codes per 4-wave block; barrier-free loop ----
__global__ __launch_bounds__(BLOCK, 2) void vq_main(
    const float* __restrict__ z, const float* __restrict__ cb,
    const _Float16* __restrict__ ef, const float* __restrict__ cn,
    float* __restrict__ zq, float* __restrict__ idx_out) {
    __shared__ __align__(16) float zf[128 * 68];   // 34816 B, +68 stride
    __shared__ float sS[128];
    __shared__ float sCn[K];
    __shared__ int   sBi[128];

    const int tid  = threadIdx.x;
    const int lane = tid & 63;
    const int wv   = tid >> 6;
    const int quad = lane >> 4;
    const int l16  = lane & 15;
    const long rowbase = (long)blockIdx.x * 128;

    // ---- stage z (coalesced) + all code norms ----
    const float4* gz = (const float4*)(z + rowbase * D);
#pragma unroll
    for (int i = 0; i < 8; ++i) {
        int idx4 = i * BLOCK + tid;
        int r = idx4 >> 4, j = idx4 & 15;
        *(float4*)(zf + r * 68 + j * 4) = gz[idx4];
    }
#pragma unroll
    for (int i = 0; i < 4; ++i) sCn[i * 256 + tid] = cn[i * 256 + tid];
    __syncthreads();

    // row norms (exact np chain)
    if (tid < 128) sS[tid] = np_sumsq64_p(zf + tid * 68);

    // A-frags: register-resident f16 splits; wave wv -> rows wv*32 .. +31
    half8_t a1[2][2], a2[2][2];
#pragma unroll
    for (int rt = 0; rt < 2; ++rt) {
        const int row = wv * 32 + rt * 16 + l16;
#pragma unroll
        for (int ch = 0; ch < 2; ++ch) {
            const float* p = zf + row * 68 + ch * 32 + quad * 8;
            float4 f0 = *(const float4*)(p);
            float4 f1 = *(const float4*)(p + 4);
            float xs[8] = {f0.x, f0.y, f0.z, f0.w, f1.x, f1.y, f1.z, f1.w};
#pragma unroll
            for (int j = 0; j < 8; ++j) {
                _Float16 h1 = (_Float16)xs[j];
                a1[rt][ch][j] = h1;
                a2[rt][ch][j] =
                    (_Float16)(__fmul_rn(__fsub_rn(xs[j], (float)h1), 2048.0f));
            }
        }
    }
    __syncthreads();   // sS visible to all waves

    float myS[2][4];
#pragma unroll
    for (int rt = 0; rt < 2; ++rt)
#pragma unroll
        for (int r = 0; r < 4; ++r)
            myS[rt][r] = sS[wv * 32 + rt * 16 + quad * 4 + r];

    float bv[2][4];
    int   bi[2][4];
#pragma unroll
    for (int rt = 0; rt < 2; ++rt)
#pragma unroll
        for (int r = 0; r < 4; ++r) { bv[rt][r] = INFINITY; bi[rt][r] = 0; }

    const char* eb = (const char*)ef + 16 * lane;
    const floatx4 Z4g = {0.f, 0.f, 0.f, 0.f};      // single zero acc quad

// 4 x global_load_dwordx4 in ONE volatile asm block: cannot be collapsed,
// sunk, or serialized by the compiler. Early-clobber keeps the address
// pair out of the destination quads. + cnv LDS prefetch (compiler lgkmcnt).
#define GLD4(b1_, b2_, cnv_, g_) do {                                         \
        const char* p_ = eb + (size_t)(g_) * 4096;                            \
        asm volatile(                                                         \
            "global_load_dwordx4 %0, %4, off\n\t"                             \
            "global_load_dwordx4 %1, %4, off offset:1024\n\t"                 \
            "global_load_dwordx4 %2, %4, off offset:2048\n\t"                 \
            "global_load_dwordx4 %3, %4, off offset:3072"                     \
            : "=&v"(b1_[0]), "=&v"(b1_[1]), "=&v"(b2_[0]), "=&v"(b2_[1])      \
            : "v"(p_));                                                       \
        cnv_ = sCn[(g_) * 16 + l16];                                          \
    } while (0)

// counted wait: allow N outstanding (never 0 in steady state) + rule #18
// fence so MFMAs cannot hoist past the wait.
#define VWAIT(N_) do {                                                        \
        asm volatile("s_waitcnt vmcnt(" N_ ")");                              \
        __builtin_amdgcn_sched_barrier(0);                                    \
    } while (0)

// 12 MFMAs (rt0/rt1 interleaved; per-element accumulation order = R8)
// + exact EPI: ds=fma(aC,2^-11,aM); t2=ds*2^-9; dist=(S-t2)+cn; strict <.
#define COMPUTE(b1_, b2_, cnv_, g_) do {                                      \
        const int kg_ = (g_) * 16 + l16;                                      \
        floatx4 aM0, aM1, aC0, aC1;                                           \
        aM0 = __builtin_amdgcn_mfma_f32_16x16x32_f16(a1[0][0], b1_[0], Z4g, 0, 0, 0); \
        aM1 = __builtin_amdgcn_mfma_f32_16x16x32_f16(a1[1][0], b1_[0], Z4g, 0, 0, 0); \
        aM0 = __builtin_amdgcn_mfma_f32_16x16x32_f16(a1[0][1], b1_[1], aM0, 0, 0, 0); \
        aM1 = __builtin_amdgcn_mfma_f32_16x16x32_f16(a1[1][1], b1_[1], aM1, 0, 0, 0); \
        aC0 = __builtin_amdgcn_mfma_f32_16x16x32_f16(a1[0][0], b2_[0], Z4g, 0, 0, 0); \
        aC1 = __builtin_amdgcn_mfma_f32_16x16x32_f16(a1[1][0], b2_[0], Z4g, 0, 0, 0); \
        aC0 = __builtin_amdgcn_mfma_f32_16x16x32_f16(a1[0][1], b2_[1], aC0, 0, 0, 0); \
        aC1 = __builtin_amdgcn_mfma_f32_16x16x32_f16(a1[1][1], b2_[1], aC1, 0, 0, 0); \
        aC0 = __builtin_amdgcn_mfma_f32_16x16x32_f16(a2[0][0], b1_[0], aC0, 0, 0, 0); \
        aC1 = __builtin_amdgcn_mfma_f32_16x16x32_f16(a2[1][0], b1_[0], aC1, 0, 0, 0); \
        aC0 = __builtin_amdgcn_mfma_f32_16x16x32_f16(a2[0][1], b1_[1], aC0, 0, 0, 0); \
        aC1 = __builtin_amdgcn_mfma_f32_16x16x32_f16(a2[1][1], b1_[1], aC1, 0, 0, 0); \
        _Pragma("unroll")                                                     \
        for (int r = 0; r < 4; ++r) {                                         \
            float ds0 = fmaf(aC0[r], 0x1p-11f, aM0[r]);                       \
            float d0  = __fadd_rn(__fsub_rn(myS[0][r],                        \
                            __fmul_rn(ds0, 0x1p-9f)), cnv_);                  \
            if (d0 < bv[0][r]) { bv[0][r] = d0; bi[0][r] = kg_; }             \
            float ds1 = fmaf(aC1[r], 0x1p-11f, aM1[r]);                       \
            float d1  = __fadd_rn(__fsub_rn(myS[1][r],                        \
                            __fmul_rn(ds1, 0x1p-9f)), cnv_);                  \
            if (d1 < bv[1][r]) { bv[1][r] = d1; bi[1][r] = kg_; }             \
        }                                                                     \
    } while (0)

    // depth-4 asm pipeline over 64 groups: 16 loads in flight, each slot
    // waited 3 compute-groups (~900cy) after issue. No workgroup barriers.
    half8_t b1A[2], b2A[2], b1B[2], b2B[2], b1C[2], b2C[2], b1D[2], b2D[2];
    float cnvA, cnvB, cnvC, cnvD;
    GLD4(b1A, b2A, cnvA, 0);
    GLD4(b1B, b2B, cnvB, 1);
    GLD4(b1C, b2C, cnvC, 2);
    for (int g = 0; g < 60; g += 4) {
        GLD4(b1D, b2D, cnvD, g + 3);
        VWAIT("12");
        COMPUTE(b1A, b2A, cnvA, g);
        GLD4(b1A, b2A, cnvA, g + 4);
        VWAIT("12");
        COMPUTE(b1B, b2B, cnvB, g + 1);
        GLD4(b1B, b2B, cnvB, g + 5);
        VWAIT("12");
        COMPUTE(b1C, b2C, cnvC, g + 2);
        GLD4(b1C, b2C, cnvC, g + 6);
        VWAIT("12");
        COMPUTE(b1D, b2D, cnvD, g + 3);
    }
    // tail: groups 60..63 (loads 60,61,62 issued in the g=56 iteration)
    GLD4(b1D, b2D, cnvD, 63);
    VWAIT("12");
    COMPUTE(b1A, b2A, cnvA, 60);
    VWAIT("8");
    COMPUTE(b1B, b2B, cnvB, 61);
    VWAIT("4");
    COMPUTE(b1C, b2C, cnvC, 62);
    VWAIT("0");
    COMPUTE(b1D, b2D, cnvD, 63);

#undef GLD4
#undef VWAIT
#undef COMPUTE

    // reduce over the 16 code-columns; (val, lowest index) = first occurrence
#pragma unroll
    for (int rt = 0; rt < 2; ++rt)
#pragma unroll
        for (int r = 0; r < 4; ++r) {
            float v = bv[rt][r];
            int   x = bi[rt][r];
#pragma unroll
            for (int off = 1; off <= 8; off <<= 1) {
                float ov = __shfl_xor(v, off);
                int   ox = __shfl_xor(x, off);
                if (ov < v || (ov == v && ox < x)) { v = ov; x = ox; }
            }
            if (l16 == 0) {
                const int rl = wv * 32 + rt * 16 + quad * 4 + r;
                sBi[rl] = x;
                idx_out[rowbase + rl] = (float)x;
            }
        }
    __syncthreads();

    // ---- zq gather: zq[row] = cb[bi[row]] (cb L2-hot, coalesced writes) ----
    const float4* cb4 = (const float4*)cb;
    float4* zq4 = (float4*)(zq + rowbase * D);
#pragma unroll
    for (int i = 0; i < 8; ++i) {
        int idx4 = i * BLOCK + tid;
        int r = idx4 >> 4, j = idx4 & 15;
        zq4[idx4] = cb4[(long)sBi[r] * 16 + j];
    }
}

extern "C" void kernel_launch(void* const* d_in, const int* in_sizes, int n_in,
                              void* d_out, int out_size, void* d_ws, size_t ws_size,
                              hipStream_t stream) {
    const float* z  = (const float*)d_in[0];
    const float* cb = (const float*)d_in[1];

    const int n_rows = in_sizes[0] / D;                 // 65536
    float* zq      = (float*)d_out;
    float* idx_out = zq + (long)n_rows * D;

    float*    ws_cn = (float*)((char*)d_ws + WS_CN_OFF);
    _Float16* ws_ef = (_Float16*)((char*)d_ws + WS_EF_OFF);

    vq_pre<<<K / 64, 64, 0, stream>>>(cb, ws_cn, ws_ef);
    vq_main<<<n_rows / 128, BLOCK, 0, stream>>>(z, cb, ws_ef, ws_cn, zq, idx_out);
}